// Round 1
// baseline (15071.562 us; speedup 1.0000x reference)
//
#include <hip/hip_runtime.h>

typedef __bf16 bf16x8 __attribute__((ext_vector_type(8)));
typedef float f32x4 __attribute__((ext_vector_type(4)));

#define T_STEPS 1024
#define H_SZ    1024
#define F_IN    256
#define NGROUP  4
#define NB      16   // batches per group
#define WPG     64   // workgroups per group

__device__ __forceinline__ unsigned short f2bf(float f) {
    union { float f; unsigned u; } v; v.f = f;
    unsigned r = v.u + 0x7fffu + ((v.u >> 16) & 1u);
    return (unsigned short)(r >> 16);
}

__device__ __forceinline__ float fsigmoid(float x) {
    return 1.0f / (1.0f + __expf(-x));
}
__device__ __forceinline__ float ftanh(float x) {
    // tanh(x) = 1 - 2/(exp(2x)+1); saturates correctly for large |x|
    return 1.0f - 2.0f / (__expf(2.0f * x) + 1.0f);
}

// ---------------------------------------------------------------------------
// Gaussian blur (sigma=1, radius=4, edge padding), both axes fused.
// Grid: 1024 blocks = 64 batches x 16 T-chunks of 64 rows. Block: 256 (=F).
// Writes bf16 x_blur [B][T][F].
// ---------------------------------------------------------------------------
__global__ __launch_bounds__(256) void blur_kernel(
    const float* __restrict__ x, unsigned short* __restrict__ xb)
{
    __shared__ float tb[64][256];   // 64 KB: T-blurred chunk
    const float kk[9] = {
        0.000133831f, 0.0044318617f, 0.0539911273f, 0.2419714457f,
        0.3989434694f,
        0.2419714457f, 0.0539911273f, 0.0044318617f, 0.000133831f };

    const int b     = blockIdx.x >> 4;
    const int chunk = blockIdx.x & 15;
    const int t0    = chunk * 64;
    const int f     = threadIdx.x;
    const float* xbase = x + (size_t)b * T_STEPS * F_IN;

    for (int r = 0; r < 64; r++) {
        int t = t0 + r;
        float acc = 0.0f;
        #pragma unroll
        for (int d = 0; d < 9; d++) {
            int ts = t + d - 4;
            ts = min(max(ts, 0), T_STEPS - 1);
            acc += kk[d] * xbase[ts * F_IN + f];
        }
        tb[r][f] = acc;
    }
    __syncthreads();
    for (int r = 0; r < 64; r++) {
        float acc = 0.0f;
        #pragma unroll
        for (int d = 0; d < 9; d++) {
            int fs = f + d - 4;
            fs = min(max(fs, 0), F_IN - 1);
            acc += kk[d] * tb[r][fs];
        }
        xb[((size_t)b * T_STEPS + t0 + r) * F_IN + f] = f2bf(acc);
    }
}

// ---------------------------------------------------------------------------
// Persistent LSTM kernel. 256 blocks x 256 threads, cooperative launch.
// Group g (blockIdx>>6) owns batches [16g,16g+16). WG w (blockIdx&63) owns
// hidden units [16w,16w+16) => gate rows {k*1024+16w..+16, k=0..3}.
// Waves split K. W_hh slice: 32 A-frags/lane (128 VGPR). W_ih: 8 (32 VGPR).
// ---------------------------------------------------------------------------
__global__ __launch_bounds__(256, 1) void lstm_persist(
    const unsigned short* __restrict__ xb,   // [64][1024][256] bf16
    const float* __restrict__ Whh,           // [4096][1024]
    const float* __restrict__ Wih,           // [4096][256]
    const float* __restrict__ bih,           // [4096]
    const float* __restrict__ bhh,           // [4096]
    unsigned short* __restrict__ hbuf,       // [2][64][1024] bf16
    unsigned int* __restrict__ arrive)       // [4][1024]
{
    const int wg   = blockIdx.x;
    const int grp  = wg >> 6;
    const int w    = wg & 63;
    const int tid  = threadIdx.x;
    const int q    = tid >> 6;        // wave id = K-quarter
    const int lane = tid & 63;
    const int lrow = lane & 15;       // A: m-row / B: n-col (batch)
    const int lq   = lane >> 4;       // quad

    __shared__ float part[4][4][16][16];       // [q][gate][col=batch][row=hid]
    __shared__ unsigned short hstage[NB][16];  // h slice staging

    // ---- load weight fragments (one-time), fp32 -> bf16 ----
    bf16x8 wa[8][4];   // [kt][gate]  K-quarter of W_hh
    bf16x8 wx[2][4];   // [kt][gate]  K-quarter of W_ih
    const int row_lo = w * 16 + lrow;
    #pragma unroll
    for (int kt = 0; kt < 8; kt++) {
        const int kofs = q * 256 + kt * 32 + lq * 8;
        #pragma unroll
        for (int g = 0; g < 4; g++) {
            const float* src = Whh + (size_t)(g * H_SZ + row_lo) * H_SZ + kofs;
            union { bf16x8 v; unsigned short s[8]; } u;
            #pragma unroll
            for (int j = 0; j < 8; j++) u.s[j] = f2bf(src[j]);
            wa[kt][g] = u.v;
        }
    }
    #pragma unroll
    for (int kt = 0; kt < 2; kt++) {
        const int kofs = q * 64 + kt * 32 + lq * 8;
        #pragma unroll
        for (int g = 0; g < 4; g++) {
            const float* src = Wih + (size_t)(g * H_SZ + row_lo) * F_IN + kofs;
            union { bf16x8 v; unsigned short s[8]; } u;
            #pragma unroll
            for (int j = 0; j < 8; j++) u.s[j] = f2bf(src[j]);
            wx[kt][g] = u.v;
        }
    }

    // ---- per-thread update-phase state: thread <-> (hid,batch) fixed ----
    const int uhid = tid & 15;
    const int ub   = tid >> 4;
    float bias[4];
    #pragma unroll
    for (int g = 0; g < 4; g++) {
        int r = g * H_SZ + w * 16 + uhid;
        bias[g] = bih[r] + bhh[r];
    }
    float c_reg = 0.0f;

    const int b_abs_l = grp * NB + lrow;   // batch for B-frags (this lane)
    const unsigned short* xrow_base =
        xb + ((size_t)b_abs_l * T_STEPS) * F_IN + q * 64 + lq * 8;

    for (int t = 0; t < T_STEPS; t++) {
        // ---- B-operand loads (h_{t-1} and x_blur[t]), global -> VGPR ----
        const unsigned short* hprev =
            hbuf + (size_t)((t & 1) ^ 1) * 64 * H_SZ
                 + (size_t)b_abs_l * H_SZ + q * 256 + lq * 8;
        bf16x8 hf[8];
        #pragma unroll
        for (int kt = 0; kt < 8; kt++)
            hf[kt] = *reinterpret_cast<const bf16x8*>(hprev + kt * 32);
        bf16x8 xf[2];
        const unsigned short* xrow = xrow_base + (size_t)t * F_IN;
        #pragma unroll
        for (int kt = 0; kt < 2; kt++)
            xf[kt] = *reinterpret_cast<const bf16x8*>(xrow + kt * 32);

        // ---- MFMA: gates partial over this wave's K range ----
        f32x4 acc[4];
        #pragma unroll
        for (int g = 0; g < 4; g++) acc[g] = (f32x4){0.f, 0.f, 0.f, 0.f};
        #pragma unroll
        for (int kt = 0; kt < 8; kt++)
            #pragma unroll
            for (int g = 0; g < 4; g++)
                acc[g] = __builtin_amdgcn_mfma_f32_16x16x32_bf16(
                    wa[kt][g], hf[kt], acc[g], 0, 0, 0);
        #pragma unroll
        for (int kt = 0; kt < 2; kt++)
            #pragma unroll
            for (int g = 0; g < 4; g++)
                acc[g] = __builtin_amdgcn_mfma_f32_16x16x32_bf16(
                    wx[kt][g], xf[kt], acc[g], 0, 0, 0);

        // ---- cross-wave K reduction via LDS ----
        #pragma unroll
        for (int g = 0; g < 4; g++)
            #pragma unroll
            for (int r = 0; r < 4; r++)
                part[q][g][lrow][lq * 4 + r] = acc[g][r];
        __syncthreads();

        // ---- gate nonlinearity + state update (thread = (hid,batch)) ----
        float gv[4];
        #pragma unroll
        for (int g = 0; g < 4; g++) {
            float s = bias[g];
            #pragma unroll
            for (int qq = 0; qq < 4; qq++) s += part[qq][g][ub][uhid];
            gv[g] = s;
        }
        float ig = fsigmoid(gv[0]);
        float fg = fsigmoid(gv[1]);
        float gg = ftanh(gv[2]);
        float og = fsigmoid(gv[3]);
        c_reg = fg * c_reg + ig * gg;
        float hv = og * ftanh(c_reg);
        hstage[ub][uhid] = f2bf(hv);
        __syncthreads();

        // ---- publish h slice: agent-scope write-through stores ----
        if (tid < 128) {
            int b2 = tid >> 3;   // 0..15
            int hp = tid & 7;    // hid pair
            unsigned v = (unsigned)hstage[b2][hp * 2]
                       | ((unsigned)hstage[b2][hp * 2 + 1] << 16);
            unsigned int* dst = (unsigned int*)(hbuf
                + (size_t)(t & 1) * 64 * H_SZ
                + (size_t)(grp * NB + b2) * H_SZ + w * 16 + hp * 2);
            __hip_atomic_store(dst, v, __ATOMIC_RELAXED,
                               __HIP_MEMORY_SCOPE_AGENT);
        }
        __syncthreads();   // drains vmem (compiler emits vmcnt(0) barrier)

        // ---- group barrier ----
        if (tid == 0) {
            unsigned int* ctr = &arrive[grp * T_STEPS + t];
            __hip_atomic_fetch_add(ctr, 1u, __ATOMIC_RELEASE,
                                   __HIP_MEMORY_SCOPE_AGENT);
            while (__hip_atomic_load(ctr, __ATOMIC_ACQUIRE,
                                     __HIP_MEMORY_SCOPE_AGENT) < (unsigned)WPG)
                __builtin_amdgcn_s_sleep(2);
        }
        __syncthreads();
        // invalidate stale L1/L2 copies of h before next step's loads
        __builtin_amdgcn_fence(__ATOMIC_ACQUIRE, "agent");
    }
}

// ---------------------------------------------------------------------------
// out[b][o] = h_last[b] . W_fc[o] + b_fc[o].  64 blocks x 256 threads.
// ---------------------------------------------------------------------------
__global__ __launch_bounds__(256) void final_fc(
    const unsigned short* __restrict__ hbuf,  // parity-1 holds h_last
    const float* __restrict__ Wfc, const float* __restrict__ bfc,
    float* __restrict__ out)
{
    __shared__ float hs[H_SZ];
    const int b = blockIdx.x;
    const unsigned short* hrow = hbuf + (size_t)64 * H_SZ + (size_t)b * H_SZ;
    for (int k = threadIdx.x; k < H_SZ; k += 256) {
        union { unsigned u; float f; } cv;
        cv.u = ((unsigned)hrow[k]) << 16;
        hs[k] = cv.f;
    }
    __syncthreads();
    const int o = threadIdx.x;
    const float4* wr = reinterpret_cast<const float4*>(Wfc + (size_t)o * H_SZ);
    float acc = bfc[o];
    for (int k4 = 0; k4 < H_SZ / 4; k4++) {
        float4 wv = wr[k4];
        acc += hs[k4 * 4 + 0] * wv.x + hs[k4 * 4 + 1] * wv.y
             + hs[k4 * 4 + 2] * wv.z + hs[k4 * 4 + 3] * wv.w;
    }
    out[(size_t)b * 256 + o] = acc;
}

// ---------------------------------------------------------------------------
extern "C" void kernel_launch(void* const* d_in, const int* in_sizes, int n_in,
                              void* d_out, int out_size, void* d_ws,
                              size_t ws_size, hipStream_t stream)
{
    (void)in_sizes; (void)n_in; (void)out_size; (void)ws_size;
    const float* x   = (const float*)d_in[0];
    const float* Wih = (const float*)d_in[1];
    const float* Whh = (const float*)d_in[2];
    const float* bih = (const float*)d_in[3];
    const float* bhh = (const float*)d_in[4];
    const float* Wfc = (const float*)d_in[5];
    const float* bfc = (const float*)d_in[6];
    float* out = (float*)d_out;

    char* ws = (char*)d_ws;
    unsigned short* xblur = (unsigned short*)ws;                    // 33,554,432 B
    unsigned short* hbuf  = (unsigned short*)(ws + 33554432);       // 262,144 B
    unsigned int*   arrv  = (unsigned int*)(ws + 33554432 + 262144); // 16,384 B

    // zero h0 and barrier counters (ws is poisoned before every launch)
    hipMemsetAsync(hbuf, 0, 262144 + 16384, stream);

    blur_kernel<<<dim3(1024), dim3(256), 0, stream>>>(x, xblur);

    void* kargs[] = { (void*)&xblur, (void*)&Whh, (void*)&Wih,
                      (void*)&bih, (void*)&bhh, (void*)&hbuf, (void*)&arrv };
    hipLaunchCooperativeKernel((void*)lstm_persist, dim3(256), dim3(256),
                               kargs, 0, stream);

    final_fc<<<dim3(64), dim3(256), 0, stream>>>(hbuf, Wfc, bfc, out);
}

// Round 2
// 4169.239 us; speedup vs baseline: 3.6149x; 3.6149x over previous
//
#include <hip/hip_runtime.h>

typedef __bf16 bf16x8 __attribute__((ext_vector_type(8)));
typedef float f32x4 __attribute__((ext_vector_type(4)));

#define T_STEPS 1024
#define H_SZ    1024
#define F_IN    256
#define NGROUP  4
#define NB      16   // batches per group
#define WPG     64   // workgroups per group

__device__ __forceinline__ unsigned short f2bf(float f) {
    union { float f; unsigned u; } v; v.f = f;
    unsigned r = v.u + 0x7fffu + ((v.u >> 16) & 1u);
    return (unsigned short)(r >> 16);
}

__device__ __forceinline__ float fsigmoid(float x) {
    return 1.0f / (1.0f + __expf(-x));
}
__device__ __forceinline__ float ftanh(float x) {
    return 1.0f - 2.0f / (__expf(2.0f * x) + 1.0f);
}

// ---------------------------------------------------------------------------
// Gaussian blur (sigma=1, radius=4, edge padding), both axes fused.
// ---------------------------------------------------------------------------
__global__ __launch_bounds__(256) void blur_kernel(
    const float* __restrict__ x, unsigned short* __restrict__ xb)
{
    __shared__ float tb[64][256];
    const float kk[9] = {
        0.000133831f, 0.0044318617f, 0.0539911273f, 0.2419714457f,
        0.3989434694f,
        0.2419714457f, 0.0539911273f, 0.0044318617f, 0.000133831f };

    const int b     = blockIdx.x >> 4;
    const int chunk = blockIdx.x & 15;
    const int t0    = chunk * 64;
    const int f     = threadIdx.x;
    const float* xbase = x + (size_t)b * T_STEPS * F_IN;

    for (int r = 0; r < 64; r++) {
        int t = t0 + r;
        float acc = 0.0f;
        #pragma unroll
        for (int d = 0; d < 9; d++) {
            int ts = t + d - 4;
            ts = min(max(ts, 0), T_STEPS - 1);
            acc += kk[d] * xbase[ts * F_IN + f];
        }
        tb[r][f] = acc;
    }
    __syncthreads();
    for (int r = 0; r < 64; r++) {
        float acc = 0.0f;
        #pragma unroll
        for (int d = 0; d < 9; d++) {
            int fs = f + d - 4;
            fs = min(max(fs, 0), F_IN - 1);
            acc += kk[d] * tb[r][fs];
        }
        xb[((size_t)b * T_STEPS + t0 + r) * F_IN + f] = f2bf(acc);
    }
}

// ---------------------------------------------------------------------------
// Persistent LSTM kernel. 256 blocks x 256 threads, cooperative launch.
// Cross-WG h exchange entirely through sc0/sc1 (MALL-coherent) accesses:
// NO agent acquire/release fences -> no buffer_inv / buffer_wbl2 in the loop.
// ---------------------------------------------------------------------------
__global__ __launch_bounds__(256, 1) void lstm_persist(
    const unsigned short* __restrict__ xb,   // [64][1024][256] bf16
    const float* __restrict__ Whh,           // [4096][1024]
    const float* __restrict__ Wih,           // [4096][256]
    const float* __restrict__ bih,           // [4096]
    const float* __restrict__ bhh,           // [4096]
    unsigned short* __restrict__ hbuf,       // [2][64][1024] bf16
    unsigned int* __restrict__ arrive)       // [4][1024]
{
    const int wg   = blockIdx.x;
    const int grp  = wg >> 6;
    const int w    = wg & 63;
    const int tid  = threadIdx.x;
    const int q    = tid >> 6;        // wave id = K-quarter
    const int lane = tid & 63;
    const int lrow = lane & 15;       // A: m-row / B: n-col (batch)
    const int lq   = lane >> 4;       // quad

    // [q][gate][lane] float4 accum fragments: ds_write_b128 lane-contiguous
    __shared__ f32x4 part[4][4][64];

    // ---- load weight fragments (one-time), fp32 -> bf16 ----
    bf16x8 wa[8][4];   // [kt][gate]  K-quarter of W_hh
    bf16x8 wx[2][4];   // [kt][gate]  K-quarter of W_ih
    const int row_lo = w * 16 + lrow;
    #pragma unroll
    for (int kt = 0; kt < 8; kt++) {
        const int kofs = q * 256 + kt * 32 + lq * 8;
        #pragma unroll
        for (int g = 0; g < 4; g++) {
            const float* src = Whh + (size_t)(g * H_SZ + row_lo) * H_SZ + kofs;
            union { bf16x8 v; unsigned short s[8]; } u;
            #pragma unroll
            for (int j = 0; j < 8; j++) u.s[j] = f2bf(src[j]);
            wa[kt][g] = u.v;
        }
    }
    #pragma unroll
    for (int kt = 0; kt < 2; kt++) {
        const int kofs = q * 64 + kt * 32 + lq * 8;
        #pragma unroll
        for (int g = 0; g < 4; g++) {
            const float* src = Wih + (size_t)(g * H_SZ + row_lo) * F_IN + kofs;
            union { bf16x8 v; unsigned short s[8]; } u;
            #pragma unroll
            for (int j = 0; j < 8; j++) u.s[j] = f2bf(src[j]);
            wx[kt][g] = u.v;
        }
    }

    // ---- per-thread update-phase state: thread <-> (hid,batch) fixed ----
    const int uhid = tid & 15;
    const int ub   = tid >> 4;
    float bias[4];
    #pragma unroll
    for (int g = 0; g < 4; g++) {
        int r = g * H_SZ + w * 16 + uhid;
        bias[g] = bih[r] + bhh[r];
    }
    float c_reg = 0.0f;

    const int b_abs_l = grp * NB + lrow;   // batch for B-frags (this lane)
    const unsigned short* xrow_base =
        xb + ((size_t)b_abs_l * T_STEPS) * F_IN + q * 64 + lq * 8;
    unsigned short* hdst =
        hbuf + (size_t)(grp * NB + ub) * H_SZ + w * 16 + uhid;

    for (int t = 0; t < T_STEPS; t++) {
        // ---- x fragment: normal cached loads (xb stays warm in L1/L2) ----
        const unsigned short* xrow = xrow_base + (size_t)t * F_IN;
        bf16x8 xf0 = *reinterpret_cast<const bf16x8*>(xrow);
        bf16x8 xf1 = *reinterpret_cast<const bf16x8*>(xrow + 32);

        // ---- h_{t-1} fragments: coherent loads from MALL (bypass L1/L2) ----
        const unsigned short* hprev =
            hbuf + ((size_t)((t & 1) ^ 1) * 64 + b_abs_l) * H_SZ
                 + q * 256 + lq * 8;
        bf16x8 hf0, hf1, hf2, hf3, hf4, hf5, hf6, hf7;
        asm volatile(
            "global_load_dwordx4 %0, %8, off sc0 sc1\n\t"
            "global_load_dwordx4 %1, %8, off offset:64 sc0 sc1\n\t"
            "global_load_dwordx4 %2, %8, off offset:128 sc0 sc1\n\t"
            "global_load_dwordx4 %3, %8, off offset:192 sc0 sc1\n\t"
            "global_load_dwordx4 %4, %8, off offset:256 sc0 sc1\n\t"
            "global_load_dwordx4 %5, %8, off offset:320 sc0 sc1\n\t"
            "global_load_dwordx4 %6, %8, off offset:384 sc0 sc1\n\t"
            "global_load_dwordx4 %7, %8, off offset:448 sc0 sc1\n\t"
            "s_waitcnt vmcnt(0)"
            : "=&v"(hf0), "=&v"(hf1), "=&v"(hf2), "=&v"(hf3),
              "=&v"(hf4), "=&v"(hf5), "=&v"(hf6), "=&v"(hf7)
            : "v"(hprev)
            : "memory");
        bf16x8 hfa[8] = { hf0, hf1, hf2, hf3, hf4, hf5, hf6, hf7 };

        // ---- MFMA: gates partial over this wave's K range ----
        f32x4 acc[4];
        #pragma unroll
        for (int g = 0; g < 4; g++) acc[g] = (f32x4){0.f, 0.f, 0.f, 0.f};
        #pragma unroll
        for (int kt = 0; kt < 8; kt++)
            #pragma unroll
            for (int g = 0; g < 4; g++)
                acc[g] = __builtin_amdgcn_mfma_f32_16x16x32_bf16(
                    wa[kt][g], hfa[kt], acc[g], 0, 0, 0);
        acc[0] = __builtin_amdgcn_mfma_f32_16x16x32_bf16(wx[0][0], xf0, acc[0], 0, 0, 0);
        acc[1] = __builtin_amdgcn_mfma_f32_16x16x32_bf16(wx[0][1], xf0, acc[1], 0, 0, 0);
        acc[2] = __builtin_amdgcn_mfma_f32_16x16x32_bf16(wx[0][2], xf0, acc[2], 0, 0, 0);
        acc[3] = __builtin_amdgcn_mfma_f32_16x16x32_bf16(wx[0][3], xf0, acc[3], 0, 0, 0);
        acc[0] = __builtin_amdgcn_mfma_f32_16x16x32_bf16(wx[1][0], xf1, acc[0], 0, 0, 0);
        acc[1] = __builtin_amdgcn_mfma_f32_16x16x32_bf16(wx[1][1], xf1, acc[1], 0, 0, 0);
        acc[2] = __builtin_amdgcn_mfma_f32_16x16x32_bf16(wx[1][2], xf1, acc[2], 0, 0, 0);
        acc[3] = __builtin_amdgcn_mfma_f32_16x16x32_bf16(wx[1][3], xf1, acc[3], 0, 0, 0);

        // ---- cross-wave K reduction via LDS (b128, lane-contiguous) ----
        #pragma unroll
        for (int g = 0; g < 4; g++)
            part[q][g][lane] = acc[g];
        __syncthreads();

        // ---- gate nonlinearity + state update (thread = (hid,batch)) ----
        float gv[4];
        #pragma unroll
        for (int g = 0; g < 4; g++) {
            float s = bias[g];
            #pragma unroll
            for (int qq = 0; qq < 4; qq++)
                s += part[qq][g][(uhid >> 2) * 16 + ub][uhid & 3];
            gv[g] = s;
        }
        float ig = fsigmoid(gv[0]);
        float fg = fsigmoid(gv[1]);
        float gg = ftanh(gv[2]);
        float og = fsigmoid(gv[3]);
        c_reg = fg * c_reg + ig * gg;
        float hv = og * ftanh(c_reg);

        // ---- publish h: coherent 2B store to MALL, drained before barrier --
        unsigned short hb = f2bf(hv);
        unsigned short* dst = hdst + (size_t)(t & 1) * 64 * H_SZ;
        asm volatile(
            "global_store_short %0, %1, off sc0 sc1\n\t"
            "s_waitcnt vmcnt(0)"
            :: "v"(dst), "v"(hb)
            : "memory");
        __syncthreads();   // all threads' h stores are at MALL now

        // ---- group barrier: RELAXED add + RELAXED poll (no fences!) ----
        if (tid == 0) {
            unsigned int* ctr = &arrive[grp * T_STEPS + t];
            __hip_atomic_fetch_add(ctr, 1u, __ATOMIC_RELAXED,
                                   __HIP_MEMORY_SCOPE_AGENT);
            while (__hip_atomic_load(ctr, __ATOMIC_RELAXED,
                                     __HIP_MEMORY_SCOPE_AGENT) < (unsigned)WPG) {}
        }
        __syncthreads();
    }
}

// ---------------------------------------------------------------------------
// out[b][o] = h_last[b] . W_fc[o] + b_fc[o].  64 blocks x 256 threads.
// ---------------------------------------------------------------------------
__global__ __launch_bounds__(256) void final_fc(
    const unsigned short* __restrict__ hbuf,  // parity-1 holds h_last
    const float* __restrict__ Wfc, const float* __restrict__ bfc,
    float* __restrict__ out)
{
    __shared__ float hs[H_SZ];
    const int b = blockIdx.x;
    const unsigned short* hrow = hbuf + (size_t)64 * H_SZ + (size_t)b * H_SZ;
    for (int k = threadIdx.x; k < H_SZ; k += 256) {
        union { unsigned u; float f; } cv;
        cv.u = ((unsigned)hrow[k]) << 16;
        hs[k] = cv.f;
    }
    __syncthreads();
    const int o = threadIdx.x;
    const float4* wr = reinterpret_cast<const float4*>(Wfc + (size_t)o * H_SZ);
    float acc = bfc[o];
    for (int k4 = 0; k4 < H_SZ / 4; k4++) {
        float4 wv = wr[k4];
        acc += hs[k4 * 4 + 0] * wv.x + hs[k4 * 4 + 1] * wv.y
             + hs[k4 * 4 + 2] * wv.z + hs[k4 * 4 + 3] * wv.w;
    }
    out[(size_t)b * 256 + o] = acc;
}

// ---------------------------------------------------------------------------
extern "C" void kernel_launch(void* const* d_in, const int* in_sizes, int n_in,
                              void* d_out, int out_size, void* d_ws,
                              size_t ws_size, hipStream_t stream)
{
    (void)in_sizes; (void)n_in; (void)out_size; (void)ws_size;
    const float* x   = (const float*)d_in[0];
    const float* Wih = (const float*)d_in[1];
    const float* Whh = (const float*)d_in[2];
    const float* bih = (const float*)d_in[3];
    const float* bhh = (const float*)d_in[4];
    const float* Wfc = (const float*)d_in[5];
    const float* bfc = (const float*)d_in[6];
    float* out = (float*)d_out;

    char* ws = (char*)d_ws;
    unsigned short* xblur = (unsigned short*)ws;                     // 33,554,432 B
    unsigned short* hbuf  = (unsigned short*)(ws + 33554432);        // 262,144 B
    unsigned int*   arrv  = (unsigned int*)(ws + 33554432 + 262144); // 16,384 B

    // zero h0 and barrier counters (ws is poisoned before every launch)
    hipMemsetAsync(hbuf, 0, 262144 + 16384, stream);

    blur_kernel<<<dim3(1024), dim3(256), 0, stream>>>(x, xblur);

    void* kargs[] = { (void*)&xblur, (void*)&Whh, (void*)&Wih,
                      (void*)&bih, (void*)&bhh, (void*)&hbuf, (void*)&arrv };
    hipLaunchCooperativeKernel((void*)lstm_persist, dim3(256), dim3(256),
                               kargs, 0, stream);

    final_fc<<<dim3(64), dim3(256), 0, stream>>>(hbuf, Wfc, bfc, out);
}